// Round 2
// baseline (584.411 us; speedup 1.0000x reference)
//
#include <hip/hip_runtime.h>
#include <hip/hip_bf16.h>

typedef __hip_bfloat16 bf16;
typedef short short8 __attribute__((ext_vector_type(8)));
typedef float floatx4 __attribute__((ext_vector_type(4)));

#define S 256
#define H 512
#define P 32896            // S*(S+1)/2
#define NROWS 65792        // B*P
#define NEGF -1e30f
#define EPSF 1e-12f

// ---------------- ws layout (bytes, all 256-aligned) ----------------
#define OFF_SEQ    0u          // f32 [B*S*H]   1048576
#define OFF_CSUM   1048576u    // f32 [B*S*H]
#define OFF_TOT    2097152u    // f32 [B*8*H]   32768
#define OFF_LN1    2129920u    // f32 [B*S*H]
#define OFF_G1     3178496u    // f32 [B*S*H]
#define OFF_B1     4227072u    // f32 [B*S*H]
#define OFF_WCAT   5275648u    // bf16 [1024*512]
#define OFF_II     6324224u    // u16 [P]
#define OFF_JJ     6390016u    // u16 [P]
#define OFF_MU2    6455808u    // f32 [NROWS]
#define OFF_INV2   6718976u    // f32 [NROWS]
#define OFF_INNER  6982144u    // bf16 [NROWS*H]  67371008
#define OFF_FLAG   74353152u   // int (1 = inputs are bf16, 0 = fp32)

// flag-dispatched input load / output store (wave-uniform branch)
__device__ __forceinline__ float ldin(const void* p, size_t i, int flag) {
    return flag ? __bfloat162float(((const bf16*)p)[i]) : ((const float*)p)[i];
}
__device__ __forceinline__ void stout(void* p, size_t i, float v, int flag) {
    if (flag) ((bf16*)p)[i] = __float2bfloat16(v);
    else      ((float*)p)[i] = v;
}

// ---------------- dtype probe: mask is all-ones by construction ----------------
__global__ void probe_kernel(const unsigned* __restrict__ mask_words, int* __restrict__ flag) {
    // fp32 1.0 -> word 0x3F800000 ; bf16 [1.0,1.0] -> word 0x3F803F80
    *flag = (mask_words[0] == 0x3F800000u) ? 0 : 1;
}

// ---------------- pair index tables ----------------
__global__ void pairs_kernel(unsigned short* ii, unsigned short* jj) {
    int p = blockIdx.x * 256 + threadIdx.x;
    if (p >= P) return;
    float disc = 513.0f * 513.0f - 8.0f * (float)p;
    int i = (int)((513.0f - sqrtf(disc)) * 0.5f);
    i = i < 0 ? 0 : (i > S - 1 ? S - 1 : i);
    while (i > 0 && (i * S - i * (i - 1) / 2) > p) --i;
    while (i < S - 1 && ((i + 1) * S - (i + 1) * i / 2) <= p) ++i;
    int off = i * S - i * (i - 1) / 2;
    ii[p] = (unsigned short)i;
    jj[p] = (unsigned short)(i + (p - off));
}

// ---------------- seq + 2-level prefix scan ----------------
__global__ void seq_scan1(const void* __restrict__ x, const void* __restrict__ mask,
                          float* __restrict__ seq, float* __restrict__ tot,
                          const int* __restrict__ flagp) {
    const int flag = *flagp;
    int b = blockIdx.x >> 3, sc = blockIdx.x & 7, h = threadIdx.x;
    int s0 = sc * 32;
    float run = 0.0f;
    for (int t = 0; t < 32; ++t) {
        int s = s0 + t;
        float mk = ldin(mask, b * S + s, flag);
        float v = ldin(x, (size_t)(b * S + s) * H + h, flag) + (1.0f - mk) * (-1000.0f);
        seq[(size_t)(b * S + s) * H + h] = v;
        run += v;
    }
    tot[(size_t)blockIdx.x * H + h] = run;
}

__global__ void seq_scan2(const float* __restrict__ seq, const float* __restrict__ tot,
                          float* __restrict__ csum) {
    int b = blockIdx.x >> 3, sc = blockIdx.x & 7, h = threadIdx.x;
    float run = 0.0f;
    for (int c = 0; c < sc; ++c) run += tot[(size_t)(b * 8 + c) * H + h];
    int s0 = sc * 32;
    for (int t = 0; t < 32; ++t) {
        run += seq[(size_t)(b * S + s0 + t) * H + h];
        csum[(size_t)(b * S + s0 + t) * H + h] = run;
    }
}

// ---------------- LN1 per-row normalize (rows = B*S) ----------------
__global__ void ln1_kernel(const float* __restrict__ seq, float* __restrict__ ln1) {
    int row = blockIdx.x * 4 + (threadIdx.x >> 6);
    int lane = threadIdx.x & 63;
    const float* p = seq + (size_t)row * H;
    float v[8], sum = 0.0f, ss = 0.0f;
#pragma unroll
    for (int t = 0; t < 8; ++t) { v[t] = p[t * 64 + lane]; sum += v[t]; ss += v[t] * v[t]; }
    for (int o = 1; o < 64; o <<= 1) { sum += __shfl_xor(sum, o); ss += __shfl_xor(ss, o); }
    float m = sum * (1.0f / 512.0f);
    float var = ss * (1.0f / 512.0f) - m * m;
    var = var < 0.0f ? 0.0f : var;
    float inv = rsqrtf(var + EPSF);
    float* q = ln1 + (size_t)row * H;
#pragma unroll
    for (int t = 0; t < 8; ++t) q[t * 64 + lane] = (v[t] - m) * inv;
}

// ---------------- G1/B1 = bias + seq @ W1 (small f32 GEMM) ----------------
__global__ __launch_bounds__(512) void g1b1_kernel(
    const float* __restrict__ seq, const void* __restrict__ Wg1, const void* __restrict__ Wb1,
    const void* __restrict__ g1, const void* __restrict__ b1,
    float* __restrict__ G1, float* __restrict__ B1, const int* __restrict__ flagp) {
    const int flag = *flagp;
    __shared__ float rowbuf[8][H];
    int grp = blockIdx.x;   // 0..63
    int mat = blockIdx.y;   // 0..1
    int h = threadIdx.x;
    int r0 = grp * 8;
    for (int r = 0; r < 8; ++r) rowbuf[r][h] = seq[(size_t)(r0 + r) * H + h];
    __syncthreads();
    const void* W = mat ? Wb1 : Wg1;
    float acc[8] = {0, 0, 0, 0, 0, 0, 0, 0};
    for (int k = 0; k < H; ++k) {
        float w = ldin(W, (size_t)k * H + h, flag);
#pragma unroll
        for (int r = 0; r < 8; ++r) acc[r] += rowbuf[r][k] * w;
    }
    float bias = ldin(mat ? b1 : g1, h, flag);
    float* dst = mat ? B1 : G1;
    for (int r = 0; r < 8; ++r) dst[(size_t)(r0 + r) * H + h] = acc[r] + bias;
}

// ---------------- WcatT[n][k]: n<512 -> Wg2[k][n], else Wb2[k][n-512] ----------------
__global__ __launch_bounds__(512) void wcat_kernel(const void* __restrict__ Wg2,
                                                   const void* __restrict__ Wb2,
                                                   bf16* __restrict__ wcatT,
                                                   const int* __restrict__ flagp) {
    const int flag = *flagp;
    int n = blockIdx.x;      // 0..1023
    int k = threadIdx.x;     // 0..511
    float v = (n < H) ? ldin(Wg2, (size_t)k * H + n, flag)
                      : ldin(Wb2, (size_t)k * H + (n - H), flag);
    wcatT[(size_t)n * H + k] = __float2bfloat16(v);
}

// ---------------- inner[p][h] = lam*mean + (1-lam)*max (bf16) ----------------
__global__ __launch_bounds__(512) void inner_kernel(
    const float* __restrict__ seq, const float* __restrict__ csum,
    const void* __restrict__ lamtha, bf16* __restrict__ inner,
    const int* __restrict__ flagp) {
    const int flag = *flagp;
    int b = blockIdx.x >> 8, i = blockIdx.x & 255, h = threadIdx.x;
    float lam = ldin(lamtha, h, flag);
    const float* seqb = seq + (size_t)b * S * H;
    const float* csb = csum + (size_t)b * S * H;
    float s_i = seqb[(size_t)i * H + h];
    float c_i = csb[(size_t)i * H + h];
    float mrun = NEGF;
    size_t base = (size_t)b * P + (size_t)(i * S - i * (i - 1) / 2);
    for (int j = i; j < S; ++j) {
        float v = seqb[(size_t)j * H + h];
        float c = csb[(size_t)j * H + h];
        mrun = fmaxf(mrun, v);
        float meanv = (c - c_i + s_i) / (float)(j - i + 1);
        float iv = lam * meanv + (1.0f - lam) * mrun;
        inner[(base + (size_t)(j - i)) * H + h] = __float2bfloat16(iv);
    }
}

// ---------------- LN2 row stats: wave per pair-row ----------------
__global__ void stats_kernel(const float* __restrict__ ln1, const float* __restrict__ G1,
                             const float* __restrict__ B1,
                             const unsigned short* __restrict__ ii,
                             const unsigned short* __restrict__ jj,
                             float* __restrict__ mu2, float* __restrict__ inv2) {
    int r = blockIdx.x * 4 + (threadIdx.x >> 6);
    int lane = threadIdx.x & 63;
    int b = (r >= P) ? 1 : 0;
    int p = r - b * P;
    int i = ii[p], j = jj[p];
    const float* lp = ln1 + (size_t)(b * S + j) * H;
    const float* gp = G1 + (size_t)(b * S + i) * H;
    const float* bp = B1 + (size_t)(b * S + i) * H;
    float sum = 0.0f, ss = 0.0f;
#pragma unroll
    for (int t = 0; t < 8; ++t) {
        int h = t * 64 + lane;
        float v = lp[h] * gp[h] + bp[h];
        sum += v; ss += v * v;
    }
    for (int o = 1; o < 64; o <<= 1) { sum += __shfl_xor(sum, o); ss += __shfl_xor(ss, o); }
    if (lane == 0) {
        float m = sum * (1.0f / 512.0f);
        float var = ss * (1.0f / 512.0f) - m * m;
        var = var < 0.0f ? 0.0f : var;
        mu2[r] = m;
        inv2[r] = rsqrtf(var + EPSF);
    }
}

// ---------------- fused GEMM (inner @ [Wg2|Wb2]) + LN2 epilogue ----------------
// block: 256 thr (4 waves). tile: 128 pair-rows x 64 h-cols x {G,B}. BK=64.
// waves: wm = wave&1 (row half), wv = wave>>1 (0 = G cols, 1 = B cols).
#define APAD_ROW 144   // (64+8) bf16 = 144 B
__global__ __launch_bounds__(256) void gemm_kernel(
    const bf16* __restrict__ inner, const bf16* __restrict__ wcatT,
    const void* __restrict__ g2, const void* __restrict__ b2,
    const float* __restrict__ ln1, const float* __restrict__ G1, const float* __restrict__ B1,
    const unsigned short* __restrict__ ii, const unsigned short* __restrict__ jj,
    const float* __restrict__ mu2, const float* __restrict__ inv2,
    void* __restrict__ out, const int* __restrict__ flagp) {
    const int flag = *flagp;
    __shared__ __align__(16) char smem[36864];
    char* As = smem;                 // 128 x APAD_ROW = 18432 B
    char* Bt = smem + 18432;         // 128 x APAD_ROW
    float* bexch = (float*)smem;     // 128 x 68 f32 = 34816 B (epilogue union)

    const int tid = threadIdx.x;
    const int wave = tid >> 6, lane = tid & 63;
    const int q = lane >> 4, l15 = lane & 15;
    const int wm = wave & 1, wv = wave >> 1;
    const int htile = blockIdx.x;        // 0..7
    const int R0 = blockIdx.y * 128;     // pair-row base

    floatx4 acc[4][4];
#pragma unroll
    for (int a = 0; a < 4; ++a)
#pragma unroll
        for (int c = 0; c < 4; ++c) acc[a][c] = (floatx4){0.f, 0.f, 0.f, 0.f};

    for (int kk = 0; kk < H; kk += 64) {
        // stage A: 128 rows x 8 chunks(16B)
#pragma unroll
        for (int t = 0; t < 4; ++t) {
            int task = t * 256 + tid;
            int m = task >> 3, c = task & 7;
            int4 v = *(const int4*)(inner + (size_t)(R0 + m) * H + kk + c * 8);
            *(int4*)(As + m * APAD_ROW + c * 16) = v;
        }
        // stage B: 128 gemm-cols (64 G + 64 B) x 8 chunks
#pragma unroll
        for (int t = 0; t < 4; ++t) {
            int task = t * 256 + tid;
            int n = task >> 3, c = task & 7;
            int wrow = (n < 64) ? (htile * 64 + n) : (448 + htile * 64 + n);
            int4 v = *(const int4*)(wcatT + (size_t)wrow * H + kk + c * 8);
            *(int4*)(Bt + n * APAD_ROW + c * 16) = v;
        }
        __syncthreads();
#pragma unroll
        for (int ks = 0; ks < 2; ++ks) {
            short8 af[4], bfr[4];
#pragma unroll
            for (int f = 0; f < 4; ++f) {
                af[f] = *(const short8*)(As + (wm * 64 + f * 16 + l15) * APAD_ROW + ks * 64 + q * 16);
                bfr[f] = *(const short8*)(Bt + (wv * 64 + f * 16 + l15) * APAD_ROW + ks * 64 + q * 16);
            }
#pragma unroll
            for (int fm = 0; fm < 4; ++fm)
#pragma unroll
                for (int fn = 0; fn < 4; ++fn)
                    acc[fm][fn] = __builtin_amdgcn_mfma_f32_16x16x32_bf16(af[fm], bfr[fn], acc[fm][fn], 0, 0, 0);
        }
        __syncthreads();
    }

    // ---- epilogue: B-waves publish B2 = C_B + b2 through LDS ----
    if (wv == 1) {
#pragma unroll
        for (int fm = 0; fm < 4; ++fm)
#pragma unroll
            for (int fn = 0; fn < 4; ++fn)
#pragma unroll
                for (int r = 0; r < 4; ++r) {
                    int m = wm * 64 + fm * 16 + q * 4 + r;
                    int col = fn * 16 + l15;
                    int h = htile * 64 + col;
                    bexch[m * 68 + col] = acc[fm][fn][r] + ldin(b2, h, flag);
                }
    }
    __syncthreads();
    if (wv == 0) {
#pragma unroll
        for (int fm = 0; fm < 4; ++fm)
#pragma unroll
            for (int r = 0; r < 4; ++r) {
                int m = wm * 64 + fm * 16 + q * 4 + r;
                int rg = R0 + m;
                int b = (rg >= P) ? 1 : 0;
                int p = rg - b * P;
                int i = ii[p], j = jj[p];
                float mu = mu2[rg], iv = inv2[rg];
                const float* lp = ln1 + (size_t)(b * S + j) * H;
                const float* gp = G1 + (size_t)(b * S + i) * H;
                const float* bp = B1 + (size_t)(b * S + i) * H;
#pragma unroll
                for (int fn = 0; fn < 4; ++fn) {
                    int col = fn * 16 + l15;
                    int h = htile * 64 + col;
                    float G2v = acc[fm][fn][r] + ldin(g2, h, flag);
                    float B2v = bexch[m * 68 + col];
                    float s = (lp[h] * gp[h] + bp[h] - mu) * iv;
                    stout(out, (size_t)rg * H + h, s * G2v + B2v, flag);
                }
            }
    }
}

// ---------------- launcher ----------------
extern "C" void kernel_launch(void* const* d_in, const int* in_sizes, int n_in,
                              void* d_out, int out_size, void* d_ws, size_t ws_size,
                              hipStream_t stream) {
    const void* x = d_in[0];
    const void* mask = d_in[1];
    const void* lamtha = d_in[2];
    const void* Wg1 = d_in[3];
    const void* Wb1 = d_in[4];
    const void* g1 = d_in[5];
    const void* b1 = d_in[6];
    const void* Wg2 = d_in[7];
    const void* Wb2 = d_in[8];
    const void* g2 = d_in[9];
    const void* b2 = d_in[10];

    char* ws = (char*)d_ws;
    float* seq = (float*)(ws + OFF_SEQ);
    float* csum = (float*)(ws + OFF_CSUM);
    float* tot = (float*)(ws + OFF_TOT);
    float* ln1 = (float*)(ws + OFF_LN1);
    float* G1 = (float*)(ws + OFF_G1);
    float* B1 = (float*)(ws + OFF_B1);
    bf16* wcatT = (bf16*)(ws + OFF_WCAT);
    unsigned short* iiA = (unsigned short*)(ws + OFF_II);
    unsigned short* jjA = (unsigned short*)(ws + OFF_JJ);
    float* mu2 = (float*)(ws + OFF_MU2);
    float* inv2 = (float*)(ws + OFF_INV2);
    bf16* inner = (bf16*)(ws + OFF_INNER);
    int* flagp = (int*)(ws + OFF_FLAG);

    hipLaunchKernelGGL(probe_kernel, dim3(1), dim3(1), 0, stream, (const unsigned*)mask, flagp);
    hipLaunchKernelGGL(pairs_kernel, dim3(129), dim3(256), 0, stream, iiA, jjA);
    hipLaunchKernelGGL(seq_scan1, dim3(16), dim3(512), 0, stream, x, mask, seq, tot, flagp);
    hipLaunchKernelGGL(seq_scan2, dim3(16), dim3(512), 0, stream, seq, tot, csum);
    hipLaunchKernelGGL(ln1_kernel, dim3(128), dim3(256), 0, stream, seq, ln1);
    hipLaunchKernelGGL(g1b1_kernel, dim3(64, 2), dim3(512), 0, stream, seq, Wg1, Wb1, g1, b1, G1, B1, flagp);
    hipLaunchKernelGGL(wcat_kernel, dim3(1024), dim3(512), 0, stream, Wg2, Wb2, wcatT, flagp);
    hipLaunchKernelGGL(inner_kernel, dim3(512), dim3(512), 0, stream, seq, csum, lamtha, inner, flagp);
    hipLaunchKernelGGL(stats_kernel, dim3(16448), dim3(256), 0, stream, ln1, G1, B1, iiA, jjA, mu2, inv2);
    hipLaunchKernelGGL(gemm_kernel, dim3(8, 514), dim3(256), 0, stream,
                       inner, wcatT, g2, b2, ln1, G1, B1, iiA, jjA, mu2, inv2, d_out, flagp);
}

// Round 3
// 447.002 us; speedup vs baseline: 1.3074x; 1.3074x over previous
//
#include <hip/hip_runtime.h>
#include <hip/hip_bf16.h>

typedef __hip_bfloat16 bf16;
typedef short short8 __attribute__((ext_vector_type(8)));
typedef float floatx4 __attribute__((ext_vector_type(4)));

#define S 256
#define H 512
#define P 32896            // S*(S+1)/2
#define NROWS 65792        // B*P
#define NEGF -1e30f
#define EPSF 1e-12f

// ---------------- ws layout (bytes) ----------------
#define OFF_SEQ    0u          // f32 [B*S*H]
#define OFF_CSUM   1048576u    // f32 [B*S*H]
#define OFF_LN1    2129920u    // f32 [B*S*H]
#define OFF_G1     3178496u    // f32 [B*S*H]
#define OFF_B1     4227072u    // f32 [B*S*H]
#define OFF_WCAT   5275648u    // bf16 [1024*512]
#define OFF_II     6324224u    // u16 [P]
#define OFF_JJ     6390016u    // u16 [P]
#define OFF_MU2    6455808u    // f32 [NROWS]
#define OFF_INV2   6718976u    // f32 [NROWS]
#define OFF_INNER  6982144u    // bf16 [NROWS*H]
// tot (f32 [64*H] = 128 KB) overlays the head of OFF_INNER: scan1 writes it,
// scan2 reads it, inner_kernel (later in stream) then overwrites the region.

// async 16B global->LDS (lane-linear dest: base + lane*16)
__device__ __forceinline__ void gld_lds16(const void* g, void* l) {
    __builtin_amdgcn_global_load_lds(
        (const __attribute__((address_space(1))) void*)g,
        (__attribute__((address_space(3))) void*)l, 16, 0, 0);
}

// ---------------- pair index tables ----------------
__global__ void pairs_kernel(unsigned short* ii, unsigned short* jj) {
    int p = blockIdx.x * 256 + threadIdx.x;
    if (p >= P) return;
    float disc = 513.0f * 513.0f - 8.0f * (float)p;
    int i = (int)((513.0f - sqrtf(disc)) * 0.5f);
    i = i < 0 ? 0 : (i > S - 1 ? S - 1 : i);
    while (i > 0 && (i * S - i * (i - 1) / 2) > p) --i;
    while (i < S - 1 && ((i + 1) * S - (i + 1) * i / 2) <= p) ++i;
    int off = i * S - i * (i - 1) / 2;
    ii[p] = (unsigned short)i;
    jj[p] = (unsigned short)(i + (p - off));
}

// ---------------- seq + 2-level prefix scan (64 blocks, 8 s each) ----------------
__global__ __launch_bounds__(512) void seq_scan1(const float* __restrict__ x,
                                                 const float* __restrict__ mask,
                                                 float* __restrict__ seq, float* __restrict__ tot) {
    int b = blockIdx.x >> 5, sc = blockIdx.x & 31, h = threadIdx.x;
    int s0 = sc * 8;
    float run = 0.0f;
#pragma unroll
    for (int t = 0; t < 8; ++t) {
        int s = s0 + t;
        float v = x[(size_t)(b * S + s) * H + h] + (1.0f - mask[b * S + s]) * (-1000.0f);
        seq[(size_t)(b * S + s) * H + h] = v;
        run += v;
    }
    tot[(size_t)blockIdx.x * H + h] = run;
}

__global__ __launch_bounds__(512) void seq_scan2(const float* __restrict__ seq,
                                                 const float* __restrict__ tot,
                                                 float* __restrict__ csum) {
    int b = blockIdx.x >> 5, sc = blockIdx.x & 31, h = threadIdx.x;
    float run = 0.0f;
    for (int c = 0; c < sc; ++c) run += tot[(size_t)(b * 32 + c) * H + h];
    int s0 = sc * 8;
#pragma unroll
    for (int t = 0; t < 8; ++t) {
        run += seq[(size_t)(b * S + s0 + t) * H + h];
        csum[(size_t)(b * S + s0 + t) * H + h] = run;
    }
}

// ---------------- LN1 per-row normalize (rows = B*S) ----------------
__global__ void ln1_kernel(const float* __restrict__ seq, float* __restrict__ ln1) {
    int row = blockIdx.x * 4 + (threadIdx.x >> 6);
    int lane = threadIdx.x & 63;
    const float* p = seq + (size_t)row * H;
    float v[8], sum = 0.0f, ss = 0.0f;
#pragma unroll
    for (int t = 0; t < 8; ++t) { v[t] = p[t * 64 + lane]; sum += v[t]; ss += v[t] * v[t]; }
    for (int o = 1; o < 64; o <<= 1) { sum += __shfl_xor(sum, o); ss += __shfl_xor(ss, o); }
    float m = sum * (1.0f / 512.0f);
    float var = ss * (1.0f / 512.0f) - m * m;
    var = var < 0.0f ? 0.0f : var;
    float inv = rsqrtf(var + EPSF);
    float* q = ln1 + (size_t)row * H;
#pragma unroll
    for (int t = 0; t < 8; ++t) q[t * 64 + lane] = (v[t] - m) * inv;
}

// ---------------- G1/B1 = bias + seq @ W1 (small f32 GEMM) ----------------
__global__ __launch_bounds__(512) void g1b1_kernel(
    const float* __restrict__ seq, const float* __restrict__ Wg1, const float* __restrict__ Wb1,
    const float* __restrict__ g1, const float* __restrict__ b1,
    float* __restrict__ G1, float* __restrict__ B1) {
    __shared__ float rowbuf[8][H];
    int grp = blockIdx.x;   // 0..63
    int mat = blockIdx.y;   // 0..1
    int h = threadIdx.x;
    int r0 = grp * 8;
    for (int r = 0; r < 8; ++r) rowbuf[r][h] = seq[(size_t)(r0 + r) * H + h];
    __syncthreads();
    const float* W = mat ? Wb1 : Wg1;
    float acc[8] = {0, 0, 0, 0, 0, 0, 0, 0};
#pragma unroll 4
    for (int k = 0; k < H; ++k) {
        float w = W[(size_t)k * H + h];
#pragma unroll
        for (int r = 0; r < 8; ++r) acc[r] += rowbuf[r][k] * w;
    }
    float bias = (mat ? b1 : g1)[h];
    float* dst = mat ? B1 : G1;
    for (int r = 0; r < 8; ++r) dst[(size_t)(r0 + r) * H + h] = acc[r] + bias;
}

// ---------------- WcatT[n][k]: n<512 -> Wg2[k][n], else Wb2[k][n-512] ----------------
__global__ __launch_bounds__(512) void wcat_kernel(const float* __restrict__ Wg2,
                                                   const float* __restrict__ Wb2,
                                                   bf16* __restrict__ wcatT) {
    int n = blockIdx.x;      // 0..1023
    int k = threadIdx.x;     // 0..511
    float v = (n < H) ? Wg2[(size_t)k * H + n] : Wb2[(size_t)k * H + (n - H)];
    wcatT[(size_t)n * H + k] = __float2bfloat16(v);
}

// ---------------- inner[p][h] = lam*mean + (1-lam)*max (bf16), balanced ----------------
__global__ __launch_bounds__(512) void inner_kernel(
    const float* __restrict__ seq, const float* __restrict__ csum,
    const float* __restrict__ lamtha, bf16* __restrict__ inner) {
    int b = blockIdx.x >> 7, z = blockIdx.x & 127, h = threadIdx.x;
    float lam = lamtha[h];
    const float* seqb = seq + (size_t)b * S * H;
    const float* csb = csum + (size_t)b * S * H;
#pragma unroll
    for (int pass = 0; pass < 2; ++pass) {
        int i = pass ? (S - 1 - z) : z;
        float s_i = seqb[(size_t)i * H + h];
        float c_i = csb[(size_t)i * H + h];
        float mrun = NEGF;
        size_t base = (size_t)b * P + (size_t)(i * S - i * (i - 1) / 2);
        for (int j = i; j < S; ++j) {
            float v = seqb[(size_t)j * H + h];
            float c = csb[(size_t)j * H + h];
            mrun = fmaxf(mrun, v);
            float meanv = (c - c_i + s_i) / (float)(j - i + 1);
            float iv = lam * meanv + (1.0f - lam) * mrun;
            inner[(base + (size_t)(j - i)) * H + h] = __float2bfloat16(iv);
        }
    }
}

// ---------------- LN2 row stats: wave per pair-row ----------------
__global__ void stats_kernel(const float* __restrict__ ln1, const float* __restrict__ G1,
                             const float* __restrict__ B1,
                             const unsigned short* __restrict__ ii,
                             const unsigned short* __restrict__ jj,
                             float* __restrict__ mu2, float* __restrict__ inv2) {
    int r = blockIdx.x * 4 + (threadIdx.x >> 6);
    int lane = threadIdx.x & 63;
    int b = (r >= P) ? 1 : 0;
    int p = r - b * P;
    int i = ii[p], j = jj[p];
    const float* lp = ln1 + (size_t)(b * S + j) * H;
    const float* gp = G1 + (size_t)(b * S + i) * H;
    const float* bp = B1 + (size_t)(b * S + i) * H;
    float sum = 0.0f, ss = 0.0f;
#pragma unroll
    for (int t = 0; t < 8; ++t) {
        int h = t * 64 + lane;
        float v = lp[h] * gp[h] + bp[h];
        sum += v; ss += v * v;
    }
    for (int o = 1; o < 64; o <<= 1) { sum += __shfl_xor(sum, o); ss += __shfl_xor(ss, o); }
    if (lane == 0) {
        float m = sum * (1.0f / 512.0f);
        float var = ss * (1.0f / 512.0f) - m * m;
        var = var < 0.0f ? 0.0f : var;
        mu2[r] = m;
        inv2[r] = rsqrtf(var + EPSF);
    }
}

// ---------------- fused GEMM (inner @ [Wg2|Wb2]) + LN2 epilogue ----------------
// 256 thr (4 waves). tile: 128 pair-rows x 64 h x {G,B}. BK=64.
// A/B staged via global_load_lds (16B), XOR chunk swizzle (chunk ^ row&7) applied
// on the GLOBAL address so the lane-linear LDS DMA stays contiguous; fragment
// ds_read_b128 applies the same XOR -> max 2-way bank aliasing (free).
__global__ __launch_bounds__(256) void gemm_kernel(
    const bf16* __restrict__ inner, const bf16* __restrict__ wcatT,
    const float* __restrict__ g2, const float* __restrict__ b2,
    const float* __restrict__ ln1, const float* __restrict__ G1, const float* __restrict__ B1,
    const unsigned short* __restrict__ ii, const unsigned short* __restrict__ jj,
    const float* __restrict__ mu2, const float* __restrict__ inv2,
    float* __restrict__ out) {
    __shared__ __align__(16) char smem[32768];
    char* As = smem;                 // 128 rows x 128 B (xor-swizzled)
    char* Bs = smem + 16384;         // 128 rows x 128 B
    float* bexch = (float*)smem;     // 128 x 64 f32 (epilogue union, xor-swizzled)

    const int tid = threadIdx.x;
    const int wave = tid >> 6, lane = tid & 63;
    const int q = lane >> 4, l15 = lane & 15;
    const int wm = wave & 1, wv = wave >> 1;
    const int htile = blockIdx.x;        // 0..7
    const int R0 = blockIdx.y * 128;     // pair-row base
    const int srow = lane >> 3;          // 0..7 (row within 8-row DMA group)
    const int sxor = (lane & 7) ^ srow;  // global chunk to fetch for this lane

    floatx4 acc[4][4];
#pragma unroll
    for (int a = 0; a < 4; ++a)
#pragma unroll
        for (int c = 0; c < 4; ++c) acc[a][c] = (floatx4){0.f, 0.f, 0.f, 0.f};

    for (int kk = 0; kk < H; kk += 64) {
#pragma unroll
        for (int t = 0; t < 4; ++t) {
            int g8 = wave * 4 + t;          // 8-row group 0..15
            int m = g8 * 8 + srow;          // 0..127
            gld_lds16(inner + (size_t)(R0 + m) * H + kk + sxor * 8, As + g8 * 1024);
            int wrow = (m < 64) ? (htile * 64 + m) : (512 + htile * 64 + (m - 64));
            gld_lds16(wcatT + (size_t)wrow * H + kk + sxor * 8, Bs + g8 * 1024);
        }
        __syncthreads();
#pragma unroll
        for (int ks = 0; ks < 2; ++ks) {
            short8 af[4], bfr[4];
#pragma unroll
            for (int f = 0; f < 4; ++f) {
                int mr = wm * 64 + f * 16 + l15;
                af[f] = *(const short8*)(As + mr * 128 + (((ks * 4 + q) ^ (l15 & 7)) * 16));
                int nr = wv * 64 + f * 16 + l15;
                bfr[f] = *(const short8*)(Bs + nr * 128 + (((ks * 4 + q) ^ (l15 & 7)) * 16));
            }
#pragma unroll
            for (int fm = 0; fm < 4; ++fm)
#pragma unroll
                for (int fn = 0; fn < 4; ++fn)
                    acc[fm][fn] = __builtin_amdgcn_mfma_f32_16x16x32_bf16(af[fm], bfr[fn], acc[fm][fn], 0, 0, 0);
        }
        __syncthreads();
    }

    // ---- epilogue: B-waves publish B2 = C_B + b2 through LDS ----
    if (wv == 1) {
#pragma unroll
        for (int fm = 0; fm < 4; ++fm)
#pragma unroll
            for (int fn = 0; fn < 4; ++fn)
#pragma unroll
                for (int r = 0; r < 4; ++r) {
                    int m = wm * 64 + fm * 16 + q * 4 + r;
                    int col = fn * 16 + l15;
                    int h = htile * 64 + col;
                    bexch[m * 64 + (col ^ ((m & 4) << 2))] = acc[fm][fn][r] + b2[h];
                }
    }
    __syncthreads();
    if (wv == 0) {
#pragma unroll
        for (int fm = 0; fm < 4; ++fm)
#pragma unroll
            for (int r = 0; r < 4; ++r) {
                int m = wm * 64 + fm * 16 + q * 4 + r;
                int rg = R0 + m;
                int b = (rg >= P) ? 1 : 0;
                int p = rg - b * P;
                int i = ii[p], j = jj[p];
                float mu = mu2[rg], iv = inv2[rg];
                const float* lp = ln1 + (size_t)(b * S + j) * H;
                const float* gp = G1 + (size_t)(b * S + i) * H;
                const float* bp = B1 + (size_t)(b * S + i) * H;
#pragma unroll
                for (int fn = 0; fn < 4; ++fn) {
                    int col = fn * 16 + l15;
                    int h = htile * 64 + col;
                    float G2v = acc[fm][fn][r] + g2[h];
                    float B2v = bexch[m * 64 + (col ^ ((m & 4) << 2))];
                    float s = (lp[h] * gp[h] + bp[h] - mu) * iv;
                    out[(size_t)rg * H + h] = s * G2v + B2v;
                }
            }
    }
}

// ---------------- launcher ----------------
extern "C" void kernel_launch(void* const* d_in, const int* in_sizes, int n_in,
                              void* d_out, int out_size, void* d_ws, size_t ws_size,
                              hipStream_t stream) {
    const float* x = (const float*)d_in[0];
    const float* mask = (const float*)d_in[1];
    const float* lamtha = (const float*)d_in[2];
    const float* Wg1 = (const float*)d_in[3];
    const float* Wb1 = (const float*)d_in[4];
    const float* g1 = (const float*)d_in[5];
    const float* b1 = (const float*)d_in[6];
    const float* Wg2 = (const float*)d_in[7];
    const float* Wb2 = (const float*)d_in[8];
    const float* g2 = (const float*)d_in[9];
    const float* b2 = (const float*)d_in[10];
    float* out = (float*)d_out;

    char* ws = (char*)d_ws;
    float* seq = (float*)(ws + OFF_SEQ);
    float* csum = (float*)(ws + OFF_CSUM);
    float* ln1 = (float*)(ws + OFF_LN1);
    float* G1 = (float*)(ws + OFF_G1);
    float* B1 = (float*)(ws + OFF_B1);
    bf16* wcatT = (bf16*)(ws + OFF_WCAT);
    unsigned short* iiA = (unsigned short*)(ws + OFF_II);
    unsigned short* jjA = (unsigned short*)(ws + OFF_JJ);
    float* mu2 = (float*)(ws + OFF_MU2);
    float* inv2 = (float*)(ws + OFF_INV2);
    bf16* inner = (bf16*)(ws + OFF_INNER);
    float* tot = (float*)(ws + OFF_INNER);   // overlays inner head; consumed before inner is written

    hipLaunchKernelGGL(pairs_kernel, dim3(129), dim3(256), 0, stream, iiA, jjA);
    hipLaunchKernelGGL(seq_scan1, dim3(64), dim3(512), 0, stream, x, mask, seq, tot);
    hipLaunchKernelGGL(seq_scan2, dim3(64), dim3(512), 0, stream, seq, tot, csum);
    hipLaunchKernelGGL(ln1_kernel, dim3(128), dim3(256), 0, stream, seq, ln1);
    hipLaunchKernelGGL(g1b1_kernel, dim3(64, 2), dim3(512), 0, stream, seq, Wg1, Wb1, g1, b1, G1, B1);
    hipLaunchKernelGGL(wcat_kernel, dim3(1024), dim3(512), 0, stream, Wg2, Wb2, wcatT);
    hipLaunchKernelGGL(inner_kernel, dim3(256), dim3(512), 0, stream, seq, csum, lamtha, inner);
    hipLaunchKernelGGL(stats_kernel, dim3(16448), dim3(256), 0, stream, ln1, G1, B1, iiA, jjA, mu2, inv2);
    hipLaunchKernelGGL(gemm_kernel, dim3(8, 514), dim3(256), 0, stream,
                       inner, wcatT, g2, b2, ln1, G1, B1, iiA, jjA, mu2, inv2, out);
}

// Round 4
// 402.424 us; speedup vs baseline: 1.4522x; 1.1108x over previous
//
#include <hip/hip_runtime.h>
#include <hip/hip_bf16.h>

typedef __hip_bfloat16 bf16;
typedef short short8 __attribute__((ext_vector_type(8)));
typedef float floatx4 __attribute__((ext_vector_type(4)));

#define S 256
#define H 512
#define P 32896            // S*(S+1)/2
#define NROWS 65792        // B*P
#define NEGF -1e30f
#define EPSF 1e-12f

// ---------------- ws layout (bytes) ----------------
#define OFF_SEQ    0u          // f32 [B*S*H]
#define OFF_CSUM   1048576u    // f32 [B*S*H]
#define OFF_LN1    2129920u    // f32 [B*S*H]
#define OFF_G1     3178496u    // f32 [B*S*H]
#define OFF_B1     4227072u    // f32 [B*S*H]
#define OFF_WCAT   5275648u    // bf16 [1024*512]
#define OFF_II     6324224u    // u16 [P]
#define OFF_JJ     6390016u    // u16 [P]
#define OFF_MU2    6455808u    // f32 [NROWS]
#define OFF_INV2   6718976u    // f32 [NROWS]
#define OFF_INNER  6982144u    // bf16 [NROWS*H]
// tot (f32 [64*H] = 128 KB) overlays the head of OFF_INNER (consumed by scan2
// before inner_kernel overwrites the region).

// async 16B global->LDS (lane-linear dest: base + lane*16)
__device__ __forceinline__ void gld_lds16(const void* g, void* l) {
    __builtin_amdgcn_global_load_lds(
        (const __attribute__((address_space(1))) void*)g,
        (__attribute__((address_space(3))) void*)l, 16, 0, 0);
}

// ---------------- prep: wcat transpose (blocks 0..1023) + pair tables (1024..) ----------------
__global__ __launch_bounds__(512) void prep_kernel(const float* __restrict__ Wg2,
                                                   const float* __restrict__ Wb2,
                                                   bf16* __restrict__ wcatT,
                                                   unsigned short* __restrict__ ii,
                                                   unsigned short* __restrict__ jj) {
    if (blockIdx.x < 1024) {
        int n = blockIdx.x, k = threadIdx.x;
        float v = (n < H) ? Wg2[(size_t)k * H + n] : Wb2[(size_t)k * H + (n - H)];
        wcatT[(size_t)n * H + k] = __float2bfloat16(v);
    } else {
        int p = (blockIdx.x - 1024) * 512 + threadIdx.x;
        if (p >= P) return;
        float disc = 513.0f * 513.0f - 8.0f * (float)p;
        int i = (int)((513.0f - sqrtf(disc)) * 0.5f);
        i = i < 0 ? 0 : (i > S - 1 ? S - 1 : i);
        while (i > 0 && (i * S - i * (i - 1) / 2) > p) --i;
        while (i < S - 1 && ((i + 1) * S - (i + 1) * i / 2) <= p) ++i;
        int off = i * S - i * (i - 1) / 2;
        ii[p] = (unsigned short)i;
        jj[p] = (unsigned short)(i + (p - off));
    }
}

// ---------------- seq + partial sums + fused LN1 (64 blocks, 8 s-rows each) ----------------
__global__ __launch_bounds__(512) void seq_scan1_ln1(const float* __restrict__ x,
                                                     const float* __restrict__ mask,
                                                     float* __restrict__ seq, float* __restrict__ tot,
                                                     float* __restrict__ ln1) {
    __shared__ float part[8][8][2];
    __shared__ float rstat[8][2];
    int b = blockIdx.x >> 5, sc = blockIdx.x & 31, h = threadIdx.x;
    int wave = h >> 6, lane = h & 63;
    int s0 = sc * 8;
    float v[8];
    float run = 0.0f;
#pragma unroll
    for (int t = 0; t < 8; ++t) {
        int s = s0 + t;
        v[t] = x[(size_t)(b * S + s) * H + h] + (1.0f - mask[b * S + s]) * (-1000.0f);
        seq[(size_t)(b * S + s) * H + h] = v[t];
        run += v[t];
    }
    tot[(size_t)blockIdx.x * H + h] = run;
    // per-row (over h) block stats for LN1
#pragma unroll
    for (int t = 0; t < 8; ++t) {
        float s = v[t], q = v[t] * v[t];
        for (int o = 1; o < 64; o <<= 1) { s += __shfl_xor(s, o); q += __shfl_xor(q, o); }
        if (lane == 0) { part[wave][t][0] = s; part[wave][t][1] = q; }
    }
    __syncthreads();
    if (h < 16) {
        int row = h >> 1, st = h & 1;
        float a = 0.0f;
#pragma unroll
        for (int w = 0; w < 8; ++w) a += part[w][row][st];
        rstat[row][st] = a;
    }
    __syncthreads();
#pragma unroll
    for (int t = 0; t < 8; ++t) {
        float m = rstat[t][0] * (1.0f / 512.0f);
        float var = rstat[t][1] * (1.0f / 512.0f) - m * m;
        var = var < 0.0f ? 0.0f : var;
        float inv = rsqrtf(var + EPSF);
        ln1[(size_t)(b * S + s0 + t) * H + h] = (v[t] - m) * inv;
    }
}

__global__ __launch_bounds__(512) void seq_scan2(const float* __restrict__ seq,
                                                 const float* __restrict__ tot,
                                                 float* __restrict__ csum) {
    int b = blockIdx.x >> 5, sc = blockIdx.x & 31, h = threadIdx.x;
    float run = 0.0f;
    for (int c = 0; c < sc; ++c) run += tot[(size_t)(b * 32 + c) * H + h];
    int s0 = sc * 8;
#pragma unroll
    for (int t = 0; t < 8; ++t) {
        run += seq[(size_t)(b * S + s0 + t) * H + h];
        csum[(size_t)(b * S + s0 + t) * H + h] = run;
    }
}

// ---------------- G1/B1 = bias + seq @ W1 (small f32 GEMM) ----------------
__global__ __launch_bounds__(512) void g1b1_kernel(
    const float* __restrict__ seq, const float* __restrict__ Wg1, const float* __restrict__ Wb1,
    const float* __restrict__ g1, const float* __restrict__ b1,
    float* __restrict__ G1, float* __restrict__ B1) {
    __shared__ float rowbuf[8][H];
    int grp = blockIdx.x;   // 0..63
    int mat = blockIdx.y;   // 0..1
    int h = threadIdx.x;
    int r0 = grp * 8;
    for (int r = 0; r < 8; ++r) rowbuf[r][h] = seq[(size_t)(r0 + r) * H + h];
    __syncthreads();
    const float* W = mat ? Wb1 : Wg1;
    float acc[8] = {0, 0, 0, 0, 0, 0, 0, 0};
#pragma unroll 4
    for (int k = 0; k < H; ++k) {
        float w = W[(size_t)k * H + h];
#pragma unroll
        for (int r = 0; r < 8; ++r) acc[r] += rowbuf[r][k] * w;
    }
    float bias = (mat ? b1 : g1)[h];
    float* dst = mat ? B1 : G1;
    for (int r = 0; r < 8; ++r) dst[(size_t)(r0 + r) * H + h] = acc[r] + bias;
}

// ---------------- inner[p][h] = lam*mean + (1-lam)*max (bf16x2, balanced) ----------------
// 512 blocks x 256 thr; block id: b = id>>8, t = id&255, i = b ? 255-t : t
// -> CU pairing (id, id+256) gives 257 iters per CU slot. Each thread owns 2 h.
__global__ __launch_bounds__(256) void inner_kernel(
    const float* __restrict__ seq, const float* __restrict__ csum,
    const float* __restrict__ lamtha, bf16* __restrict__ inner) {
    int id = blockIdx.x;
    int t = id & 255, b = id >> 8;
    int i = b ? (255 - t) : t;
    int h2 = threadIdx.x;                 // float2 index, 0..255
    float2 lam = ((const float2*)lamtha)[h2];
    float2 oml = {1.0f - lam.x, 1.0f - lam.y};
    const float2* seqb = (const float2*)(seq + (size_t)b * S * H);
    const float2* csb = (const float2*)(csum + (size_t)b * S * H);
    float2 s_i = seqb[i * 256 + h2];
    float2 c_i = csb[i * 256 + h2];
    float2 mrun = {NEGF, NEGF};
    size_t base = (size_t)b * P + (size_t)(i * S - i * (i - 1) / 2);
    __hip_bfloat162* dst = (__hip_bfloat162*)inner;
    for (int j = i; j < S; ++j) {
        float2 v = seqb[j * 256 + h2];
        float2 c = csb[j * 256 + h2];
        mrun.x = fmaxf(mrun.x, v.x);
        mrun.y = fmaxf(mrun.y, v.y);
        float rl = 1.0f / (float)(j - i + 1);
        float mx = (c.x - c_i.x + s_i.x) * rl;
        float my = (c.y - c_i.y + s_i.y) * rl;
        __hip_bfloat162 o;
        o.x = __float2bfloat16(lam.x * mx + oml.x * mrun.x);
        o.y = __float2bfloat16(lam.y * my + oml.y * mrun.y);
        dst[(base + (size_t)(j - i)) * 256 + h2] = o;
    }
}

// ---------------- LN2 row stats: wave per pair-row (float4 loads) ----------------
__global__ void stats_kernel(const float* __restrict__ ln1, const float* __restrict__ G1,
                             const float* __restrict__ B1,
                             const unsigned short* __restrict__ ii,
                             const unsigned short* __restrict__ jj,
                             float* __restrict__ mu2, float* __restrict__ inv2) {
    int r = blockIdx.x * 4 + (threadIdx.x >> 6);
    int lane = threadIdx.x & 63;
    int b = (r >= P) ? 1 : 0;
    int p = r - b * P;
    int i = ii[p], j = jj[p];
    const float4* lp = (const float4*)(ln1 + (size_t)(b * S + j) * H);
    const float4* gp = (const float4*)(G1 + (size_t)(b * S + i) * H);
    const float4* bp = (const float4*)(B1 + (size_t)(b * S + i) * H);
    float sum = 0.0f, ss = 0.0f;
#pragma unroll
    for (int t = 0; t < 2; ++t) {
        int idx = t * 64 + lane;
        float4 a = lp[idx], g = gp[idx], bb = bp[idx];
        float v0 = a.x * g.x + bb.x, v1 = a.y * g.y + bb.y;
        float v2 = a.z * g.z + bb.z, v3 = a.w * g.w + bb.w;
        sum += (v0 + v1) + (v2 + v3);
        ss += (v0 * v0 + v1 * v1) + (v2 * v2 + v3 * v3);
    }
    for (int o = 1; o < 64; o <<= 1) { sum += __shfl_xor(sum, o); ss += __shfl_xor(ss, o); }
    if (lane == 0) {
        float m = sum * (1.0f / 512.0f);
        float var = ss * (1.0f / 512.0f) - m * m;
        var = var < 0.0f ? 0.0f : var;
        mu2[r] = m;
        inv2[r] = rsqrtf(var + EPSF);
    }
}

// ---------------- fused GEMM (inner @ [Wg2|Wb2]) + LN2 epilogue ----------------
// 1D grid, 4112 blocks. Decode so id%8 == rowblock%8: all 8 htiles of a
// row-block land on the SAME XCD (round-robin heuristic) temporally adjacent
// -> the 128KB A-tile is fetched from HBM once and L2-hit 7 times.
__global__ __launch_bounds__(256) void gemm_kernel(
    const bf16* __restrict__ inner, const bf16* __restrict__ wcatT,
    const float* __restrict__ g2, const float* __restrict__ b2,
    const float* __restrict__ ln1, const float* __restrict__ G1, const float* __restrict__ B1,
    const unsigned short* __restrict__ ii, const unsigned short* __restrict__ jj,
    const float* __restrict__ mu2, const float* __restrict__ inv2,
    float* __restrict__ out) {
    __shared__ __align__(16) char smem[32768];
    char* As = smem;                 // 128 rows x 128 B (xor-swizzled)
    char* Bs = smem + 16384;         // 128 rows x 128 B
    float* bexch = (float*)smem;     // 128 x 64 f32 (epilogue union, xor-swizzled)

    const int tid = threadIdx.x;
    const int wave = tid >> 6, lane = tid & 63;
    const int q = lane >> 4, l15 = lane & 15;
    const int wm = wave & 1, wv = wave >> 1;

    // XCD-aware decode: super-tiles of 8 row-blocks x 8 htiles
    const int id = blockIdx.x;
    const int super = id >> 6, w = id & 63;
    int rb, htile;
    if (super < 64) { rb = super * 8 + (w & 7); htile = w >> 3; }
    else            { rb = 512 + (w & 1);       htile = w >> 1; }
    const int R0 = rb * 128;
    const int srow = lane >> 3;          // 0..7 (row within 8-row DMA group)
    const int sxor = (lane & 7) ^ srow;  // global chunk to fetch for this lane

    floatx4 acc[4][4];
#pragma unroll
    for (int a = 0; a < 4; ++a)
#pragma unroll
        for (int c = 0; c < 4; ++c) acc[a][c] = (floatx4){0.f, 0.f, 0.f, 0.f};

    for (int kk = 0; kk < H; kk += 64) {
#pragma unroll
        for (int t = 0; t < 4; ++t) {
            int g8 = wave * 4 + t;          // 8-row group 0..15
            int m = g8 * 8 + srow;          // 0..127
            gld_lds16(inner + (size_t)(R0 + m) * H + kk + sxor * 8, As + g8 * 1024);
            int wrow = (m < 64) ? (htile * 64 + m) : (512 + htile * 64 + (m - 64));
            gld_lds16(wcatT + (size_t)wrow * H + kk + sxor * 8, Bs + g8 * 1024);
        }
        __syncthreads();
#pragma unroll
        for (int ks = 0; ks < 2; ++ks) {
            short8 af[4], bfr[4];
#pragma unroll
            for (int f = 0; f < 4; ++f) {
                int mr = wm * 64 + f * 16 + l15;
                af[f] = *(const short8*)(As + mr * 128 + (((ks * 4 + q) ^ (l15 & 7)) * 16));
                int nr = wv * 64 + f * 16 + l15;
                bfr[f] = *(const short8*)(Bs + nr * 128 + (((ks * 4 + q) ^ (l15 & 7)) * 16));
            }
#pragma unroll
            for (int fm = 0; fm < 4; ++fm)
#pragma unroll
                for (int fn = 0; fn < 4; ++fn)
                    acc[fm][fn] = __builtin_amdgcn_mfma_f32_16x16x32_bf16(af[fm], bfr[fn], acc[fm][fn], 0, 0, 0);
        }
        __syncthreads();
    }

    // ---- epilogue: B-waves publish B2 = C_B + b2 through LDS ----
    if (wv == 1) {
#pragma unroll
        for (int fm = 0; fm < 4; ++fm)
#pragma unroll
            for (int fn = 0; fn < 4; ++fn)
#pragma unroll
                for (int r = 0; r < 4; ++r) {
                    int m = wm * 64 + fm * 16 + q * 4 + r;
                    int col = fn * 16 + l15;
                    int h = htile * 64 + col;
                    bexch[m * 64 + (col ^ ((m & 4) << 2))] = acc[fm][fn][r] + b2[h];
                }
    }
    __syncthreads();
    if (wv == 0) {
#pragma unroll
        for (int fm = 0; fm < 4; ++fm)
#pragma unroll
            for (int r = 0; r < 4; ++r) {
                int m = wm * 64 + fm * 16 + q * 4 + r;
                int rg = R0 + m;
                int b = (rg >= P) ? 1 : 0;
                int p = rg - b * P;
                int i = ii[p], j = jj[p];
                float mu = mu2[rg], iv = inv2[rg];
                const float* lp = ln1 + (size_t)(b * S + j) * H;
                const float* gp = G1 + (size_t)(b * S + i) * H;
                const float* bp = B1 + (size_t)(b * S + i) * H;
#pragma unroll
                for (int fn = 0; fn < 4; ++fn) {
                    int col = fn * 16 + l15;
                    int h = htile * 64 + col;
                    float G2v = acc[fm][fn][r] + g2[h];
                    float B2v = bexch[m * 64 + (col ^ ((m & 4) << 2))];
                    float s = (lp[h] * gp[h] + bp[h] - mu) * iv;
                    out[(size_t)rg * H + h] = s * G2v + B2v;
                }
            }
    }
}

// ---------------- launcher ----------------
extern "C" void kernel_launch(void* const* d_in, const int* in_sizes, int n_in,
                              void* d_out, int out_size, void* d_ws, size_t ws_size,
                              hipStream_t stream) {
    const float* x = (const float*)d_in[0];
    const float* mask = (const float*)d_in[1];
    const float* lamtha = (const float*)d_in[2];
    const float* Wg1 = (const float*)d_in[3];
    const float* Wb1 = (const float*)d_in[4];
    const float* g1 = (const float*)d_in[5];
    const float* b1 = (const float*)d_in[6];
    const float* Wg2 = (const float*)d_in[7];
    const float* Wb2 = (const float*)d_in[8];
    const float* g2 = (const float*)d_in[9];
    const float* b2 = (const float*)d_in[10];
    float* out = (float*)d_out;

    char* ws = (char*)d_ws;
    float* seq = (float*)(ws + OFF_SEQ);
    float* csum = (float*)(ws + OFF_CSUM);
    float* ln1 = (float*)(ws + OFF_LN1);
    float* G1 = (float*)(ws + OFF_G1);
    float* B1 = (float*)(ws + OFF_B1);
    bf16* wcatT = (bf16*)(ws + OFF_WCAT);
    unsigned short* iiA = (unsigned short*)(ws + OFF_II);
    unsigned short* jjA = (unsigned short*)(ws + OFF_JJ);
    float* mu2 = (float*)(ws + OFF_MU2);
    float* inv2 = (float*)(ws + OFF_INV2);
    bf16* inner = (bf16*)(ws + OFF_INNER);
    float* tot = (float*)(ws + OFF_INNER);   // overlay; consumed before inner is written

    hipLaunchKernelGGL(prep_kernel, dim3(1089), dim3(512), 0, stream, Wg2, Wb2, wcatT, iiA, jjA);
    hipLaunchKernelGGL(seq_scan1_ln1, dim3(64), dim3(512), 0, stream, x, mask, seq, tot, ln1);
    hipLaunchKernelGGL(seq_scan2, dim3(64), dim3(512), 0, stream, seq, tot, csum);
    hipLaunchKernelGGL(g1b1_kernel, dim3(64, 2), dim3(512), 0, stream, seq, Wg1, Wb1, g1, b1, G1, B1);
    hipLaunchKernelGGL(inner_kernel, dim3(512), dim3(256), 0, stream, seq, csum, lamtha, inner);
    hipLaunchKernelGGL(stats_kernel, dim3(16448), dim3(256), 0, stream, ln1, G1, B1, iiA, jjA, mu2, inv2);
    hipLaunchKernelGGL(gemm_kernel, dim3(4112), dim3(256), 0, stream,
                       inner, wcatT, g2, b2, ln1, G1, B1, iiA, jjA, mu2, inv2, out);
}